// Round 11
// baseline (73.669 us; speedup 1.0000x reference)
//
#include <hip/hip_runtime.h>
#include <hip/hip_bf16.h>

#define NROWS 16384
#define DIM   768
#define PP    256
#define BT    64
#define EPSF  1e-6f
#define GKC   32     // k_gram K-chunk (elements; = bytes in fp8)
#define NTILE 10     // symmetric 64x64 tile pairs per block
#define NGRAM (BT * NTILE)   // 640 WGs
#define SPITCH 776   // LDS f32 pitch for psum staging
#define RPW    4     // rows per norm WG
#define NWG_N  (NROWS / RPW)   // 4096 WGs
#define F8SCALE 32.0f          // pre-scale before fp8 cast (exact pow2)
#define F8INV   (1.0f / 1024.0f) // undo SCALE^2 on raw gram entries

typedef short          bf16x8 __attribute__((ext_vector_type(8)));
typedef float          f32x4  __attribute__((ext_vector_type(4)));
typedef unsigned short us8    __attribute__((ext_vector_type(8)));

__device__ __forceinline__ unsigned short f2bf(float x) {
    __hip_bfloat16 h = __float2bfloat16(x);
    return *reinterpret_cast<unsigned short*>(&h);
}

// pack 4 f32 -> 4 fp8 e4m3 bytes (OCP on gfx950)
__device__ __forceinline__ unsigned int pk_fp8x4(float a, float b, float c, float d) {
    int w = __builtin_amdgcn_cvt_pk_fp8_f32(a, b, 0, false);
    w = __builtin_amdgcn_cvt_pk_fp8_f32(c, d, w, true);
    return (unsigned int)w;
}

// ---------------------------------------------------------------- kernel 1a
// SINGLE-STREAM pass over `in`: row norm (raw si) + fp8 premat. No LDS.
__global__ __launch_bounds__(256, 8) void k_normA(const float* __restrict__ in,
                                                  float* __restrict__ nsq_in,
                                                  unsigned char* __restrict__ in8) {
    const int r   = threadIdx.x >> 6;
    const int c   = threadIdx.x & 63;
    const int row = blockIdx.x * RPW + r;
    const float4* ip = (const float4*)(in + (size_t)row * DIM);
    float4 a[3];
#pragma unroll
    for (int k = 0; k < 3; ++k) a[k] = ip[c + 64 * k];
    float si = 0.f;
#pragma unroll
    for (int k = 0; k < 3; ++k)
        si += a[k].x*a[k].x + a[k].y*a[k].y + a[k].z*a[k].z + a[k].w*a[k].w;
#pragma unroll
    for (int o = 32; o; o >>= 1) si += __shfl_xor(si, o);
    float ii = 1.f / fmaxf(sqrtf(si), 1e-12f);
    if (c == 0) nsq_in[row] = si;            // raw squared norm
    float is = ii * F8SCALE;
#pragma unroll
    for (int k = 0; k < 3; ++k) {
        unsigned int wa = pk_fp8x4(a[k].x * is, a[k].y * is, a[k].z * is, a[k].w * is);
        *(unsigned int*)(in8 + (size_t)row * DIM + 4 * c + 256 * k) = wa;
    }
}

// ---------------------------------------------------------------- kernel 1b
// SINGLE-STREAM pass over `tg` (+ hot in8): tg norm, tg8 premat, psum
// partials, and ploss via ||in-tg||^2 = si + st - 2*dot(in,tg), with the
// cross dot from fp8 in8 (only one operand quantized; err ~2e-3/row).
__global__ __launch_bounds__(256, 4) void k_normB(const float* __restrict__ tg,
                                                  const unsigned char* __restrict__ in8,
                                                  const float* __restrict__ nsq_in,
                                                  float* __restrict__ inv_tg,
                                                  float* __restrict__ ploss,
                                                  unsigned char* __restrict__ tg8,
                                                  float* __restrict__ psum) {
    __shared__ __align__(16) float S[RPW][SPITCH];
    const int r   = threadIdx.x >> 6;
    const int c   = threadIdx.x & 63;
    const int row = blockIdx.x * RPW + r;
    const float4* tp = (const float4*)(tg + (size_t)row * DIM);
    float4 t[3];
    unsigned int wa[3];
#pragma unroll
    for (int k = 0; k < 3; ++k) {
        t[k]  = tp[c + 64 * k];
        wa[k] = *(const unsigned int*)(in8 + (size_t)row * DIM + 4 * c + 256 * k);
    }
    float st = 0.f, dq = 0.f;
#pragma unroll
    for (int k = 0; k < 3; ++k) {
        st += t[k].x*t[k].x + t[k].y*t[k].y + t[k].z*t[k].z + t[k].w*t[k].w;
        float b0 = __builtin_amdgcn_cvt_f32_fp8(wa[k], 0);
        float b1 = __builtin_amdgcn_cvt_f32_fp8(wa[k], 1);
        float b2 = __builtin_amdgcn_cvt_f32_fp8(wa[k], 2);
        float b3 = __builtin_amdgcn_cvt_f32_fp8(wa[k], 3);
        dq += b0 * t[k].x + b1 * t[k].y + b2 * t[k].z + b3 * t[k].w;
    }
#pragma unroll
    for (int o = 32; o; o >>= 1) { st += __shfl_xor(st, o); dq += __shfl_xor(dq, o); }
    float it = 1.f / fmaxf(sqrtf(st), 1e-12f);
    if (c == 0) {
        float si = nsq_in[row];
        // dq = 32 * ii * dot(in,tg)  ->  dot = dq * sqrt(si) / 32
        float draw = dq * sqrtf(si) * (1.f / F8SCALE);
        inv_tg[row] = it;
        ploss[row]  = (si + st - 2.f * draw) * (1.f / DIM);
    }
    // stage normalized tg (f32) for the fused block-sum
#pragma unroll
    for (int k = 0; k < 3; ++k) {
        float4 u = t[k];
        u.x *= it; u.y *= it; u.z *= it; u.w *= it;
        *(float4*)&S[r][4 * c + 256 * k] = u;
    }
    float ts = it * F8SCALE;
#pragma unroll
    for (int k = 0; k < 3; ++k) {
        unsigned int wt = pk_fp8x4(t[k].x * ts, t[k].y * ts, t[k].z * ts, t[k].w * ts);
        *(unsigned int*)(tg8 + (size_t)row * DIM + 4 * c + 256 * k) = wt;
    }
    __syncthreads();
#pragma unroll
    for (int q = 0; q < 3; ++q) {
        int d = threadIdx.x + 256 * q;
        float s = 0.f;
#pragma unroll
        for (int rr = 0; rr < RPW; ++rr) s += S[rr][d];
        psum[(size_t)blockIdx.x * DIM + d] = s;
    }
}

// ---------------------------------------------------------------- fallback
// combined norms (exact ploss, no premat); nsq_in slot holds inv_in here.
__global__ __launch_bounds__(256, 4) void k_norm0(const float* __restrict__ in,
                                                  const float* __restrict__ tg,
                                                  float* __restrict__ inv_in,
                                                  float* __restrict__ inv_tg,
                                                  float* __restrict__ ploss,
                                                  float* __restrict__ psum) {
    __shared__ __align__(16) float S[RPW][SPITCH];
    const int r   = threadIdx.x >> 6;
    const int c   = threadIdx.x & 63;
    const int row = blockIdx.x * RPW + r;
    const float4* ip = (const float4*)(in + (size_t)row * DIM);
    const float4* tp = (const float4*)(tg + (size_t)row * DIM);
    float4 a[3], t[3];
#pragma unroll
    for (int k = 0; k < 3; ++k) { a[k] = ip[c + 64 * k]; t[k] = tp[c + 64 * k]; }
    float si = 0.f, st = 0.f, sd = 0.f;
#pragma unroll
    for (int k = 0; k < 3; ++k) {
        si += a[k].x*a[k].x + a[k].y*a[k].y + a[k].z*a[k].z + a[k].w*a[k].w;
        st += t[k].x*t[k].x + t[k].y*t[k].y + t[k].z*t[k].z + t[k].w*t[k].w;
        float dx = a[k].x-t[k].x, dy = a[k].y-t[k].y, dz = a[k].z-t[k].z, dw = a[k].w-t[k].w;
        sd += dx*dx + dy*dy + dz*dz + dw*dw;
    }
#pragma unroll
    for (int o = 32; o; o >>= 1) {
        si += __shfl_xor(si, o); st += __shfl_xor(st, o); sd += __shfl_xor(sd, o);
    }
    float ii = 1.f / fmaxf(sqrtf(si), 1e-12f);
    float it = 1.f / fmaxf(sqrtf(st), 1e-12f);
    if (c == 0) { inv_in[row] = ii; inv_tg[row] = it; ploss[row] = sd * (1.f / DIM); }
#pragma unroll
    for (int k = 0; k < 3; ++k) {
        float4 u = t[k];
        u.x *= it; u.y *= it; u.z *= it; u.w *= it;
        *(float4*)&S[r][4 * c + 256 * k] = u;
    }
    __syncthreads();
#pragma unroll
    for (int q = 0; q < 3; ++q) {
        int d = threadIdx.x + 256 * q;
        float s = 0.f;
#pragma unroll
        for (int rr = 0; rr < RPW; ++rr) s += S[rr][d];
        psum[(size_t)blockIdx.x * DIM + d] = s;
    }
}

// ------------------------------------------- weights pipeline (all f32!)
// tf/idf denominators are near-zero means — bf16/fp8 upstream of the
// reciprocals flips signs (round-3 failure). Everything here stays f32.

__global__ __launch_bounds__(256) void k_bsum2(const float* __restrict__ psum,
                                               float* __restrict__ bsum) {
    int b = blockIdx.x, d = blockIdx.y * 256 + threadIdx.x;
    float s = 0.f;
#pragma unroll 8
    for (int i = 0; i < 64; ++i)
        s += psum[(size_t)(b * 64 + i) * DIM + d];
    bsum[b * DIM + d] = s;
}

__global__ __launch_bounds__(256) void k_gmean(const float* __restrict__ bsum,
                                               float* __restrict__ va) {
    int d = blockIdx.x * 256 + threadIdx.x;
    float g = 0.f;
    for (int b = 0; b < BT; ++b) g += bsum[b * DIM + d];
    va[d] = g * (1.f / NROWS);
}

__global__ __launch_bounds__(256) void k_wdots(const float* __restrict__ tg,
                                               const float* __restrict__ inv_tg,
                                               const float* __restrict__ bsum,
                                               const float* __restrict__ va,
                                               float* __restrict__ wraw) {
    int wave = threadIdx.x >> 6, lane = threadIdx.x & 63;
    int gw = blockIdx.x * 4 + wave;
#pragma unroll
    for (int rr = 0; rr < 4; ++rr) {
        int row = gw * 4 + rr;
        int b   = row >> 8;
        const float4* t4 = (const float4*)(tg + (size_t)row * DIM);
        const float4* b4 = (const float4*)(bsum + b * DIM);
        const float4* a4 = (const float4*)va;
        float db = 0.f, da = 0.f;
#pragma unroll
        for (int v = 0; v < 3; ++v) {
            float4 t = t4[lane + 64 * v];
            float4 x = b4[lane + 64 * v];
            float4 y = a4[lane + 64 * v];
            db += t.x * x.x + t.y * x.y + t.z * x.z + t.w * x.w;
            da += t.x * y.x + t.y * y.y + t.z * y.z + t.w * y.w;
        }
#pragma unroll
        for (int o = 32; o; o >>= 1) { db += __shfl_xor(db, o); da += __shfl_xor(da, o); }
        if (lane == 0) {
            float itg = inv_tg[row];
            db *= itg; da *= itg;
            wraw[row] = (1.f / (db * (1.f / PP) + EPSF)) * (1.f / (da + EPSF));
        }
    }
}

__global__ __launch_bounds__(256) void k_wfinal(const float* __restrict__ wraw,
                                                const float* __restrict__ ploss,
                                                float* __restrict__ weights,
                                                float* __restrict__ simpart) {
    __shared__ float red[256];
    int b = blockIdx.x, p = threadIdx.x, row = b * PP + p;
    float w = wraw[row];
    red[p] = w; __syncthreads();
    for (int s = 128; s; s >>= 1) { if (p < s) red[p] += red[p + s]; __syncthreads(); }
    float wn = w / (red[0] + EPSF);
    weights[row] = wn;
    __syncthreads();
    red[p] = wn * ploss[row]; __syncthreads();
    for (int s = 128; s; s >>= 1) { if (p < s) red[p] += red[p + s]; __syncthreads(); }
    if (p == 0) simpart[b] = red[0];
}

// ---------------------------------------------------------------- kernel 4
// Dual-gram from fp8(x32) premat: 640 WGs = 64 blocks x 10 symmetric 64x64
// tile pairs; 4 waves, each a 32x32 quadrant of BOTH grams via
// mfma_f32_16x16x32_fp8_fp8. Double-buffered 16 KB LDS, one barrier/K-step.
__global__ __launch_bounds__(256, 4) void k_gram(const unsigned char* __restrict__ in8,
                                                 const unsigned char* __restrict__ tg8,
                                                 const float* __restrict__ weights,
                                                 float* __restrict__ grampart) {
    __shared__ __align__(16) unsigned char L[2][4][64 * GKC];
    __shared__ float red[256];

    const int wg  = blockIdx.x;
    const int xcd = wg & 7, j = wg >> 3;          // 640 = 8 XCD chunks x 80
    const int b   = xcd * 8 + j / NTILE;
    const int t   = j % NTILE;
    int ti, tj;
    if (t < 4)      { ti = 0; tj = t; }
    else if (t < 7) { ti = 1; tj = t - 3; }
    else if (t < 9) { ti = 2; tj = t - 5; }
    else            { ti = 3; tj = 3; }
    const int pr = ti * 64, qc = tj * 64;
    const bool diag = (ti == tj);
    const float factor = diag ? 1.f : 2.f;
    const int bP = b * PP;

    const int tid = threadIdx.x, lane = tid & 63, wave = tid >> 6;

    const unsigned char* smat = (wave & 1) ? tg8 : in8;
    const int  srow0   = bP + ((wave < 2) ? pr : qc);
    const bool doStage = !(diag && wave >= 2);
    const int  srl = lane >> 2;
    const int  scc = lane & 3;
    const int  wcc = scc ^ (srl & 3);

    unsigned long long sreg[4];
    auto LD = [&](int k0) {
        if (!doStage) return;
#pragma unroll
        for (int i = 0; i < 4; ++i)
            sreg[i] = *(const unsigned long long*)(smat + (size_t)(srow0 + 16 * i + srl) * DIM + k0 + scc * 8);
    };
    auto WR = [&](int cur) {
        if (!doStage) return;
#pragma unroll
        for (int i = 0; i < 4; ++i)
            *(unsigned long long*)&L[cur][wave][(16 * i + srl) * GKC + wcc * 8] = sreg[i];
    };

    const int ar0 = (wave >> 1) * 32, bc0 = (wave & 1) * 32;
    const int rl = lane & 15, kc = lane >> 4;
    const int bi_ = diag ? 0 : 2, bt_ = diag ? 1 : 3;

    f32x4 accI[2][2], accT[2][2];
#pragma unroll
    for (int m = 0; m < 2; ++m)
#pragma unroll
        for (int n = 0; n < 2; ++n) {
            f32x4 z = { 0.f, 0.f, 0.f, 0.f };
            accI[m][n] = z; accT[m][n] = z;
        }

    LD(0); WR(0);
    int cur = 0;
    const int NS = DIM / GKC;   // 24
    for (int ks = 0; ks < NS; ++ks) {
        if (ks + 1 < NS) LD((ks + 1) * GKC);
        __syncthreads();
        long long aI[2], aT[2], bI[2], bT[2];
#pragma unroll
        for (int m = 0; m < 2; ++m) {
            int row = ar0 + m * 16 + rl;
            int off = row * GKC + ((kc ^ (row & 3)) << 3);
            aI[m] = *(const long long*)&L[cur][0][off];
            aT[m] = *(const long long*)&L[cur][1][off];
        }
#pragma unroll
        for (int n = 0; n < 2; ++n) {
            int row = bc0 + n * 16 + rl;
            int off = row * GKC + ((kc ^ (row & 3)) << 3);
            bI[n] = *(const long long*)&L[cur][bi_][off];
            bT[n] = *(const long long*)&L[cur][bt_][off];
        }
#pragma unroll
        for (int m = 0; m < 2; ++m)
#pragma unroll
            for (int n = 0; n < 2; ++n) {
                accI[m][n] = __builtin_amdgcn_mfma_f32_16x16x32_fp8_fp8(aI[m], bI[n], accI[m][n], 0, 0, 0);
                accT[m][n] = __builtin_amdgcn_mfma_f32_16x16x32_fp8_fp8(aT[m], bT[n], accT[m][n], 0, 0, 0);
            }
        if (ks + 1 < NS) WR(cur ^ 1);
        cur ^= 1;
    }

    const int r4 = lane >> 4, cl = lane & 15;
    float wq[2], wp[2][4];
#pragma unroll
    for (int n = 0; n < 2; ++n) wq[n] = weights[bP + qc + bc0 + n * 16 + cl];
#pragma unroll
    for (int m = 0; m < 2; ++m)
#pragma unroll
        for (int r = 0; r < 4; ++r) wp[m][r] = weights[bP + pr + ar0 + m * 16 + r4 * 4 + r];
    float local = 0.f;
#pragma unroll
    for (int m = 0; m < 2; ++m)
#pragma unroll
        for (int n = 0; n < 2; ++n)
#pragma unroll
            for (int r = 0; r < 4; ++r) {
                float d = (accI[m][n][r] - accT[m][n][r]) * F8INV;
                local += wp[m][r] * wq[n] * d * d;
            }
    local *= factor;
    red[tid] = local; __syncthreads();
    for (int s = 128; s; s >>= 1) { if (tid < s) red[tid] += red[tid + s]; __syncthreads(); }
    if (tid == 0) grampart[wg] = red[0];
}

// ------------------------------------------- fallback gram (f32 staging,
// bf16 MFMA, inv-norm in epilogue) — used only if workspace too small.
__global__ __launch_bounds__(256, 3) void k_gram_f32(const float* __restrict__ in,
                                                     const float* __restrict__ tg,
                                                     const float* __restrict__ inv_in,
                                                     const float* __restrict__ inv_tg,
                                                     const float* __restrict__ weights,
                                                     float* __restrict__ grampart) {
    __shared__ __align__(16) unsigned short L[2][4][64 * GKC];
    __shared__ float red[256];

    const int wg  = blockIdx.x;
    const int xcd = wg & 7, j = wg >> 3;
    const int b   = xcd * 8 + j / NTILE;
    const int t   = j % NTILE;
    int ti, tj;
    if (t < 4)      { ti = 0; tj = t; }
    else if (t < 7) { ti = 1; tj = t - 3; }
    else if (t < 9) { ti = 2; tj = t - 5; }
    else            { ti = 3; tj = 3; }
    const int pr = ti * 64, qc = tj * 64;
    const bool diag = (ti == tj);
    const float factor = diag ? 1.f : 2.f;
    const int bP = b * PP;

    const int tid = threadIdx.x, lane = tid & 63, wave = tid >> 6;

    const float* smat = (wave & 1) ? tg : in;
    const int  srow0   = bP + ((wave < 2) ? pr : qc);
    const bool doStage = !(diag && wave >= 2);
    const int  srl = lane >> 2;
    const int  scc = lane & 3;
    const int  wcc = scc ^ (srl & 3);

    float4 p0[4], p1[4];
    auto LD = [&](int k0) {
        if (!doStage) return;
#pragma unroll
        for (int i = 0; i < 4; ++i) {
            const float* base = smat + (size_t)(srow0 + 16 * i + srl) * DIM + k0 + scc * 8;
            p0[i] = *(const float4*)base;
            p1[i] = *(const float4*)(base + 4);
        }
    };
    auto WR = [&](int cur) {
        if (!doStage) return;
#pragma unroll
        for (int i = 0; i < 4; ++i) {
            us8 v;
            v[0] = f2bf(p0[i].x); v[1] = f2bf(p0[i].y);
            v[2] = f2bf(p0[i].z); v[3] = f2bf(p0[i].w);
            v[4] = f2bf(p1[i].x); v[5] = f2bf(p1[i].y);
            v[6] = f2bf(p1[i].z); v[7] = f2bf(p1[i].w);
            *(us8*)&L[cur][wave][(16 * i + srl) * GKC + wcc * 8] = v;
        }
    };

    const int ar0 = (wave >> 1) * 32, bc0 = (wave & 1) * 32;
    const int rl = lane & 15, kc = lane >> 4;
    const int bi_ = diag ? 0 : 2, bt_ = diag ? 1 : 3;

    f32x4 accI[2][2], accT[2][2];
#pragma unroll
    for (int m = 0; m < 2; ++m)
#pragma unroll
        for (int n = 0; n < 2; ++n) {
            f32x4 z = { 0.f, 0.f, 0.f, 0.f };
            accI[m][n] = z; accT[m][n] = z;
        }

    LD(0); WR(0);
    int cur = 0;
    const int NS = DIM / GKC;
    for (int ks = 0; ks < NS; ++ks) {
        if (ks + 1 < NS) LD((ks + 1) * GKC);
        __syncthreads();
        bf16x8 aI[2], aT[2], bI[2], bT[2];
#pragma unroll
        for (int m = 0; m < 2; ++m) {
            int row = ar0 + m * 16 + rl;
            int off = row * GKC + ((kc ^ (row & 3)) << 3);
            aI[m] = *(const bf16x8*)&L[cur][0][off];
            aT[m] = *(const bf16x8*)&L[cur][1][off];
        }
#pragma unroll
        for (int n = 0; n < 2; ++n) {
            int row = bc0 + n * 16 + rl;
            int off = row * GKC + ((kc ^ (row & 3)) << 3);
            bI[n] = *(const bf16x8*)&L[cur][bi_][off];
            bT[n] = *(const bf16x8*)&L[cur][bt_][off];
        }
#pragma unroll
        for (int m = 0; m < 2; ++m)
#pragma unroll
            for (int n = 0; n < 2; ++n) {
                accI[m][n] = __builtin_amdgcn_mfma_f32_16x16x32_bf16(aI[m], bI[n], accI[m][n], 0, 0, 0);
                accT[m][n] = __builtin_amdgcn_mfma_f32_16x16x32_bf16(aT[m], bT[n], accT[m][n], 0, 0, 0);
            }
        if (ks + 1 < NS) WR(cur ^ 1);
        cur ^= 1;
    }

    const int r4 = lane >> 4, cl = lane & 15;
    float wq[2], qI[2], qT[2];
#pragma unroll
    for (int n = 0; n < 2; ++n) {
        int q = bP + qc + bc0 + n * 16 + cl;
        wq[n] = weights[q]; qI[n] = inv_in[q]; qT[n] = inv_tg[q];
    }
    float wp[2][4], pI[2][4], pT[2][4];
#pragma unroll
    for (int m = 0; m < 2; ++m)
#pragma unroll
        for (int r = 0; r < 4; ++r) {
            int p = bP + pr + ar0 + m * 16 + r4 * 4 + r;
            wp[m][r] = weights[p]; pI[m][r] = inv_in[p]; pT[m][r] = inv_tg[p];
        }
    float local = 0.f;
#pragma unroll
    for (int m = 0; m < 2; ++m)
#pragma unroll
        for (int n = 0; n < 2; ++n)
#pragma unroll
            for (int r = 0; r < 4; ++r) {
                float d = accI[m][n][r] * pI[m][r] * qI[n]
                        - accT[m][n][r] * pT[m][r] * qT[n];
                local += wp[m][r] * wq[n] * d * d;
            }
    local *= factor;
    red[tid] = local; __syncthreads();
    for (int s = 128; s; s >>= 1) { if (tid < s) red[tid] += red[tid + s]; __syncthreads(); }
    if (tid == 0) grampart[wg] = red[0];
}

// ---------------------------------------------------------------- kernel 5
__global__ __launch_bounds__(256) void k_final(const float* __restrict__ simpart,
                                               const float* __restrict__ grampart,
                                               int ngram,
                                               float* __restrict__ out) {
    __shared__ float red[256];
    int t = threadIdx.x;
    float v = (t < BT) ? simpart[t] : 0.f;
    float g = 0.f;
    for (int i = t; i < ngram; i += 256) g += grampart[i];
    v += 10.f * g;
    red[t] = v; __syncthreads();
    for (int s = 128; s; s >>= 1) { if (t < s) red[t] += red[t + s]; __syncthreads(); }
    if (t == 0) out[0] = red[0] * (1.f / BT);
}

// ---------------------------------------------------------------- launch
extern "C" void kernel_launch(void* const* d_in, const int* in_sizes, int n_in,
                              void* d_out, int out_size, void* d_ws, size_t ws_size,
                              hipStream_t stream) {
    (void)in_sizes; (void)n_in; (void)out_size;
    const float* in = (const float*)d_in[0];
    const float* tg = (const float*)d_in[1];

    const size_t f8Bytes   = (size_t)NROWS * DIM;          // one fp8 matrix (12.6 MB)
    const size_t floatsOff = 2 * f8Bytes;
    const size_t fCount    = 5 * (size_t)NROWS + (size_t)NWG_N * DIM
                           + (size_t)BT * DIM + DIM + BT + NGRAM;
    const size_t needed    = floatsOff + fCount * 4;
    const bool   pre       = ws_size >= needed;

    char* wsb = (char*)d_ws;
    unsigned char* in8 = nullptr;
    unsigned char* tg8 = nullptr;
    float* fbase;
    if (pre) {
        in8   = (unsigned char*)wsb;
        tg8   = (unsigned char*)(wsb + f8Bytes);
        fbase = (float*)(wsb + floatsOff);
    } else {
        fbase = (float*)wsb;
    }
    float* nsq_in  = fbase;                 // PRE: raw si; fallback: inv_in
    float* inv_tg  = fbase + NROWS;
    float* ploss   = fbase + 2 * (size_t)NROWS;
    float* wraw    = fbase + 3 * (size_t)NROWS;
    float* weights = fbase + 4 * (size_t)NROWS;
    float* psum    = fbase + 5 * (size_t)NROWS;            // NWG_N*DIM (12.6 MB)
    float* bsum    = psum + (size_t)NWG_N * DIM;           // BT*DIM
    float* va      = bsum + (size_t)BT * DIM;              // DIM
    float* simpart = va + DIM;                             // BT
    float* grampart= simpart + BT;                         // NGRAM

    if (pre) {
        k_normA<<<NWG_N, 256, 0, stream>>>(in, nsq_in, in8);
        k_normB<<<NWG_N, 256, 0, stream>>>(tg, in8, nsq_in, inv_tg, ploss, tg8, psum);
    } else {
        k_norm0<<<NWG_N, 256, 0, stream>>>(in, tg, nsq_in, inv_tg, ploss, psum);
    }
    k_bsum2<<<dim3(BT, 3), 256, 0, stream>>>(psum, bsum);
    k_gmean<<<3, 256, 0, stream>>>(bsum, va);
    k_wdots<<<NROWS / 16, 256, 0, stream>>>(tg, inv_tg, bsum, va, wraw);
    k_wfinal<<<BT, 256, 0, stream>>>(wraw, ploss, weights, simpart);
    if (pre) {
        k_gram<<<NGRAM, 256, 0, stream>>>(in8, tg8, weights, grampart);
    } else {
        k_gram_f32<<<NGRAM, 256, 0, stream>>>(in, tg, nsq_in, inv_tg, weights, grampart);
    }
    k_final<<<1, 256, 0, stream>>>(simpart, grampart, NGRAM, (float*)d_out);
}

// Round 12
// 68.308 us; speedup vs baseline: 1.0785x; 1.0785x over previous
//
#include <hip/hip_runtime.h>
#include <hip/hip_bf16.h>

#define NROWS 16384
#define DIM   768
#define PP    256
#define BT    64
#define EPSF  1e-6f
#define GKC   32     // k_gram K-chunk (elements; = bytes in fp8)
#define NTILE 10     // symmetric 64x64 tile pairs per block
#define NGRAM (BT * NTILE)   // 640 WGs
#define SPITCH 776   // LDS f32 pitch for psum staging
#define RPW    8     // rows per norm WG (512 threads, wave per row)
#define NWG_N  (NROWS / RPW)   // 2048 WGs
#define F8SCALE 32.0f          // pre-scale before fp8 cast (exact pow2)
#define F8INV   (1.0f / 1024.0f) // undo SCALE^2 on raw gram entries

typedef short          bf16x8 __attribute__((ext_vector_type(8)));
typedef float          f32x4  __attribute__((ext_vector_type(4)));
typedef unsigned short us8    __attribute__((ext_vector_type(8)));

__device__ __forceinline__ unsigned short f2bf(float x) {
    __hip_bfloat16 h = __float2bfloat16(x);
    return *reinterpret_cast<unsigned short*>(&h);
}

// pack 4 f32 -> 4 fp8 e4m3 bytes (OCP on gfx950)
__device__ __forceinline__ unsigned int pk_fp8x4(float a, float b, float c, float d) {
    int w = __builtin_amdgcn_cvt_pk_fp8_f32(a, b, 0, false);
    w = __builtin_amdgcn_cvt_pk_fp8_f32(c, d, w, true);
    return (unsigned int)w;
}

// ---------------------------------------------------------------- kernel 1
// Per-row inv-norms + patch_loss + fused partial block-sum of normalized
// target rows + fp8(e4m3, x32) premat. 512 threads = 8 waves, wave per row.
template<int PRE>
__global__ __launch_bounds__(512, 8) void k_norms(const float* __restrict__ in,
                                                  const float* __restrict__ tg,
                                                  float* __restrict__ inv_in,
                                                  float* __restrict__ inv_tg,
                                                  float* __restrict__ ploss,
                                                  unsigned char* __restrict__ in8,
                                                  unsigned char* __restrict__ tg8,
                                                  float* __restrict__ psum) {
    __shared__ __align__(16) float S[RPW][SPITCH];   // 24.8 KB
    const int r   = threadIdx.x >> 6;          // row within WG (0..7)
    const int c   = threadIdx.x & 63;          // lane
    const int row = blockIdx.x * RPW + r;
    const float4* ip = (const float4*)(in + (size_t)row * DIM);
    const float4* tp = (const float4*)(tg + (size_t)row * DIM);
    float4 a[3], t[3];
#pragma unroll
    for (int k = 0; k < 3; ++k) { a[k] = ip[c + 64 * k]; t[k] = tp[c + 64 * k]; }
    float si = 0.f, st = 0.f, sd = 0.f;
#pragma unroll
    for (int k = 0; k < 3; ++k) {
        si += a[k].x*a[k].x + a[k].y*a[k].y + a[k].z*a[k].z + a[k].w*a[k].w;
        st += t[k].x*t[k].x + t[k].y*t[k].y + t[k].z*t[k].z + t[k].w*t[k].w;
        float dx = a[k].x-t[k].x, dy = a[k].y-t[k].y, dz = a[k].z-t[k].z, dw = a[k].w-t[k].w;
        sd += dx*dx + dy*dy + dz*dz + dw*dw;
    }
#pragma unroll
    for (int o = 32; o; o >>= 1) {
        si += __shfl_xor(si, o); st += __shfl_xor(st, o); sd += __shfl_xor(sd, o);
    }
    float ii = 1.f / fmaxf(sqrtf(si), 1e-12f);
    float it = 1.f / fmaxf(sqrtf(st), 1e-12f);
    if (c == 0) { inv_in[row] = ii; inv_tg[row] = it; ploss[row] = sd * (1.f / DIM); }

    // stage normalized tg (f32) for the fused block-sum
#pragma unroll
    for (int k = 0; k < 3; ++k) {
        float4 u = t[k];
        u.x *= it; u.y *= it; u.z *= it; u.w *= it;
        *(float4*)&S[r][4 * c + 256 * k] = u;
    }

    if constexpr (PRE != 0) {
        float is = ii * F8SCALE, ts = it * F8SCALE;
#pragma unroll
        for (int k = 0; k < 3; ++k) {
            unsigned int wa = pk_fp8x4(a[k].x * is, a[k].y * is, a[k].z * is, a[k].w * is);
            unsigned int wt = pk_fp8x4(t[k].x * ts, t[k].y * ts, t[k].z * ts, t[k].w * ts);
            *(unsigned int*)(in8 + (size_t)row * DIM + 4 * c + 256 * k) = wa;
            *(unsigned int*)(tg8 + (size_t)row * DIM + 4 * c + 256 * k) = wt;
        }
    }

    __syncthreads();
    // deterministic 8-row reduce: thread t handles d = t, t+512 (guarded)
#pragma unroll
    for (int q = 0; q < 2; ++q) {
        int d = threadIdx.x + 512 * q;
        if (d < DIM) {
            float s = 0.f;
#pragma unroll
            for (int rr = 0; rr < RPW; ++rr) s += S[rr][d];
            psum[(size_t)blockIdx.x * DIM + d] = s;
        }
    }
}

// ------------------------------------------- weights pipeline (all f32!)
// tf/idf denominators are near-zero means with values at the eps=1e-6 pole
// scale — bf16/fp8 dot error ~1e-6 lands ON the pole (round-3 absmax 1.68).
// Everything feeding the reciprocals stays f32.

// merge 32 psum partials per block -> bsum[b][d]
__global__ __launch_bounds__(256) void k_bsum2(const float* __restrict__ psum,
                                               float* __restrict__ bsum) {
    int b = blockIdx.x, d = blockIdx.y * 256 + threadIdx.x;
    float s = 0.f;
#pragma unroll 8
    for (int i = 0; i < 32; ++i)
        s += psum[(size_t)(b * 32 + i) * DIM + d];
    bsum[b * DIM + d] = s;
}

// global mean vector
__global__ __launch_bounds__(256) void k_gmean(const float* __restrict__ bsum,
                                               float* __restrict__ va) {
    int d = blockIdx.x * 256 + threadIdx.x;
    float g = 0.f;
    for (int b = 0; b < BT; ++b) g += bsum[b * DIM + d];
    va[d] = g * (1.f / NROWS);
}

__global__ __launch_bounds__(256) void k_wdots(const float* __restrict__ tg,
                                               const float* __restrict__ inv_tg,
                                               const float* __restrict__ bsum,
                                               const float* __restrict__ va,
                                               float* __restrict__ wraw) {
    int wave = threadIdx.x >> 6, lane = threadIdx.x & 63;
    int gw = blockIdx.x * 4 + wave;
#pragma unroll
    for (int rr = 0; rr < 4; ++rr) {
        int row = gw * 4 + rr;
        int b   = row >> 8;
        const float4* t4 = (const float4*)(tg + (size_t)row * DIM);
        const float4* b4 = (const float4*)(bsum + b * DIM);
        const float4* a4 = (const float4*)va;
        float db = 0.f, da = 0.f;
#pragma unroll
        for (int v = 0; v < 3; ++v) {
            float4 t = t4[lane + 64 * v];
            float4 x = b4[lane + 64 * v];
            float4 y = a4[lane + 64 * v];
            db += t.x * x.x + t.y * x.y + t.z * x.z + t.w * x.w;
            da += t.x * y.x + t.y * y.y + t.z * y.z + t.w * y.w;
        }
#pragma unroll
        for (int o = 32; o; o >>= 1) { db += __shfl_xor(db, o); da += __shfl_xor(da, o); }
        if (lane == 0) {
            float itg = inv_tg[row];
            db *= itg; da *= itg;
            wraw[row] = (1.f / (db * (1.f / PP) + EPSF)) * (1.f / (da + EPSF));
        }
    }
}

__global__ __launch_bounds__(256) void k_wfinal(const float* __restrict__ wraw,
                                                const float* __restrict__ ploss,
                                                float* __restrict__ weights,
                                                float* __restrict__ simpart) {
    __shared__ float red[256];
    int b = blockIdx.x, p = threadIdx.x, row = b * PP + p;
    float w = wraw[row];
    red[p] = w; __syncthreads();
    for (int s = 128; s; s >>= 1) { if (p < s) red[p] += red[p + s]; __syncthreads(); }
    float wn = w / (red[0] + EPSF);
    weights[row] = wn;
    __syncthreads();
    red[p] = wn * ploss[row]; __syncthreads();
    for (int s = 128; s; s >>= 1) { if (p < s) red[p] += red[p + s]; __syncthreads(); }
    if (p == 0) simpart[b] = red[0];
}

// ---------------------------------------------------------------- kernel 4
// Dual-gram from fp8(x32) premat: 640 WGs = 64 blocks x 10 symmetric 64x64
// tile pairs; 4 waves, each a 32x32 quadrant of BOTH grams via
// mfma_f32_16x16x32_fp8_fp8. Double-buffered 16 KB LDS, one barrier/K-step.
__global__ __launch_bounds__(256, 4) void k_gram(const unsigned char* __restrict__ in8,
                                                 const unsigned char* __restrict__ tg8,
                                                 const float* __restrict__ weights,
                                                 float* __restrict__ grampart) {
    __shared__ __align__(16) unsigned char L[2][4][64 * GKC];
    __shared__ float red[256];

    const int wg  = blockIdx.x;
    const int xcd = wg & 7, j = wg >> 3;          // 640 = 8 XCD chunks x 80
    const int b   = xcd * 8 + j / NTILE;
    const int t   = j % NTILE;
    int ti, tj;
    if (t < 4)      { ti = 0; tj = t; }
    else if (t < 7) { ti = 1; tj = t - 3; }
    else if (t < 9) { ti = 2; tj = t - 5; }
    else            { ti = 3; tj = 3; }
    const int pr = ti * 64, qc = tj * 64;
    const bool diag = (ti == tj);
    const float factor = diag ? 1.f : 2.f;
    const int bP = b * PP;

    const int tid = threadIdx.x, lane = tid & 63, wave = tid >> 6;

    const unsigned char* smat = (wave & 1) ? tg8 : in8;
    const int  srow0   = bP + ((wave < 2) ? pr : qc);
    const bool doStage = !(diag && wave >= 2);
    const int  srl = lane >> 2;
    const int  scc = lane & 3;
    const int  wcc = scc ^ (srl & 3);

    unsigned long long sreg[4];
    auto LD = [&](int k0) {
        if (!doStage) return;
#pragma unroll
        for (int i = 0; i < 4; ++i)
            sreg[i] = *(const unsigned long long*)(smat + (size_t)(srow0 + 16 * i + srl) * DIM + k0 + scc * 8);
    };
    auto WR = [&](int cur) {
        if (!doStage) return;
#pragma unroll
        for (int i = 0; i < 4; ++i)
            *(unsigned long long*)&L[cur][wave][(16 * i + srl) * GKC + wcc * 8] = sreg[i];
    };

    const int ar0 = (wave >> 1) * 32, bc0 = (wave & 1) * 32;
    const int rl = lane & 15, kc = lane >> 4;
    const int bi_ = diag ? 0 : 2, bt_ = diag ? 1 : 3;

    f32x4 accI[2][2], accT[2][2];
#pragma unroll
    for (int m = 0; m < 2; ++m)
#pragma unroll
        for (int n = 0; n < 2; ++n) {
            f32x4 z = { 0.f, 0.f, 0.f, 0.f };
            accI[m][n] = z; accT[m][n] = z;
        }

    LD(0); WR(0);
    int cur = 0;
    const int NS = DIM / GKC;   // 24
    for (int ks = 0; ks < NS; ++ks) {
        if (ks + 1 < NS) LD((ks + 1) * GKC);
        __syncthreads();
        long long aI[2], aT[2], bI[2], bT[2];
#pragma unroll
        for (int m = 0; m < 2; ++m) {
            int row = ar0 + m * 16 + rl;
            int off = row * GKC + ((kc ^ (row & 3)) << 3);
            aI[m] = *(const long long*)&L[cur][0][off];
            aT[m] = *(const long long*)&L[cur][1][off];
        }
#pragma unroll
        for (int n = 0; n < 2; ++n) {
            int row = bc0 + n * 16 + rl;
            int off = row * GKC + ((kc ^ (row & 3)) << 3);
            bI[n] = *(const long long*)&L[cur][bi_][off];
            bT[n] = *(const long long*)&L[cur][bt_][off];
        }
#pragma unroll
        for (int m = 0; m < 2; ++m)
#pragma unroll
            for (int n = 0; n < 2; ++n) {
                accI[m][n] = __builtin_amdgcn_mfma_f32_16x16x32_fp8_fp8(aI[m], bI[n], accI[m][n], 0, 0, 0);
                accT[m][n] = __builtin_amdgcn_mfma_f32_16x16x32_fp8_fp8(aT[m], bT[n], accT[m][n], 0, 0, 0);
            }
        if (ks + 1 < NS) WR(cur ^ 1);
        cur ^= 1;
    }

    const int r4 = lane >> 4, cl = lane & 15;
    float wq[2], wp[2][4];
#pragma unroll
    for (int n = 0; n < 2; ++n) wq[n] = weights[bP + qc + bc0 + n * 16 + cl];
#pragma unroll
    for (int m = 0; m < 2; ++m)
#pragma unroll
        for (int r = 0; r < 4; ++r) wp[m][r] = weights[bP + pr + ar0 + m * 16 + r4 * 4 + r];
    float local = 0.f;
#pragma unroll
    for (int m = 0; m < 2; ++m)
#pragma unroll
        for (int n = 0; n < 2; ++n)
#pragma unroll
            for (int r = 0; r < 4; ++r) {
                float d = (accI[m][n][r] - accT[m][n][r]) * F8INV;
                local += wp[m][r] * wq[n] * d * d;
            }
    local *= factor;
    red[tid] = local; __syncthreads();
    for (int s = 128; s; s >>= 1) { if (tid < s) red[tid] += red[tid + s]; __syncthreads(); }
    if (tid == 0) grampart[wg] = red[0];
}

// ------------------------------------------- fallback gram (f32 staging,
// bf16 MFMA, inv-norm in epilogue) — used only if workspace too small.
__global__ __launch_bounds__(256, 3) void k_gram_f32(const float* __restrict__ in,
                                                     const float* __restrict__ tg,
                                                     const float* __restrict__ inv_in,
                                                     const float* __restrict__ inv_tg,
                                                     const float* __restrict__ weights,
                                                     float* __restrict__ grampart) {
    __shared__ __align__(16) unsigned short L[2][4][64 * GKC];
    __shared__ float red[256];

    const int wg  = blockIdx.x;
    const int xcd = wg & 7, j = wg >> 3;
    const int b   = xcd * 8 + j / NTILE;
    const int t   = j % NTILE;
    int ti, tj;
    if (t < 4)      { ti = 0; tj = t; }
    else if (t < 7) { ti = 1; tj = t - 3; }
    else if (t < 9) { ti = 2; tj = t - 5; }
    else            { ti = 3; tj = 3; }
    const int pr = ti * 64, qc = tj * 64;
    const bool diag = (ti == tj);
    const float factor = diag ? 1.f : 2.f;
    const int bP = b * PP;

    const int tid = threadIdx.x, lane = tid & 63, wave = tid >> 6;

    const float* smat = (wave & 1) ? tg : in;
    const int  srow0   = bP + ((wave < 2) ? pr : qc);
    const bool doStage = !(diag && wave >= 2);
    const int  srl = lane >> 2;
    const int  scc = lane & 3;
    const int  wcc = scc ^ (srl & 3);

    float4 p0[4], p1[4];
    auto LD = [&](int k0) {
        if (!doStage) return;
#pragma unroll
        for (int i = 0; i < 4; ++i) {
            const float* base = smat + (size_t)(srow0 + 16 * i + srl) * DIM + k0 + scc * 8;
            p0[i] = *(const float4*)base;
            p1[i] = *(const float4*)(base + 4);
        }
    };
    auto WR = [&](int cur) {
        if (!doStage) return;
#pragma unroll
        for (int i = 0; i < 4; ++i) {
            us8 v;
            v[0] = f2bf(p0[i].x); v[1] = f2bf(p0[i].y);
            v[2] = f2bf(p0[i].z); v[3] = f2bf(p0[i].w);
            v[4] = f2bf(p1[i].x); v[5] = f2bf(p1[i].y);
            v[6] = f2bf(p1[i].z); v[7] = f2bf(p1[i].w);
            *(us8*)&L[cur][wave][(16 * i + srl) * GKC + wcc * 8] = v;
        }
    };

    const int ar0 = (wave >> 1) * 32, bc0 = (wave & 1) * 32;
    const int rl = lane & 15, kc = lane >> 4;
    const int bi_ = diag ? 0 : 2, bt_ = diag ? 1 : 3;

    f32x4 accI[2][2], accT[2][2];
#pragma unroll
    for (int m = 0; m < 2; ++m)
#pragma unroll
        for (int n = 0; n < 2; ++n) {
            f32x4 z = { 0.f, 0.f, 0.f, 0.f };
            accI[m][n] = z; accT[m][n] = z;
        }

    LD(0); WR(0);
    int cur = 0;
    const int NS = DIM / GKC;
    for (int ks = 0; ks < NS; ++ks) {
        if (ks + 1 < NS) LD((ks + 1) * GKC);
        __syncthreads();
        bf16x8 aI[2], aT[2], bI[2], bT[2];
#pragma unroll
        for (int m = 0; m < 2; ++m) {
            int row = ar0 + m * 16 + rl;
            int off = row * GKC + ((kc ^ (row & 3)) << 3);
            aI[m] = *(const bf16x8*)&L[cur][0][off];
            aT[m] = *(const bf16x8*)&L[cur][1][off];
        }
#pragma unroll
        for (int n = 0; n < 2; ++n) {
            int row = bc0 + n * 16 + rl;
            int off = row * GKC + ((kc ^ (row & 3)) << 3);
            bI[n] = *(const bf16x8*)&L[cur][bi_][off];
            bT[n] = *(const bf16x8*)&L[cur][bt_][off];
        }
#pragma unroll
        for (int m = 0; m < 2; ++m)
#pragma unroll
            for (int n = 0; n < 2; ++n) {
                accI[m][n] = __builtin_amdgcn_mfma_f32_16x16x32_bf16(aI[m], bI[n], accI[m][n], 0, 0, 0);
                accT[m][n] = __builtin_amdgcn_mfma_f32_16x16x32_bf16(aT[m], bT[n], accT[m][n], 0, 0, 0);
            }
        if (ks + 1 < NS) WR(cur ^ 1);
        cur ^= 1;
    }

    const int r4 = lane >> 4, cl = lane & 15;
    float wq[2], qI[2], qT[2];
#pragma unroll
    for (int n = 0; n < 2; ++n) {
        int q = bP + qc + bc0 + n * 16 + cl;
        wq[n] = weights[q]; qI[n] = inv_in[q]; qT[n] = inv_tg[q];
    }
    float wp[2][4], pI[2][4], pT[2][4];
#pragma unroll
    for (int m = 0; m < 2; ++m)
#pragma unroll
        for (int r = 0; r < 4; ++r) {
            int p = bP + pr + ar0 + m * 16 + r4 * 4 + r;
            wp[m][r] = weights[p]; pI[m][r] = inv_in[p]; pT[m][r] = inv_tg[p];
        }
    float local = 0.f;
#pragma unroll
    for (int m = 0; m < 2; ++m)
#pragma unroll
        for (int n = 0; n < 2; ++n)
#pragma unroll
            for (int r = 0; r < 4; ++r) {
                float d = accI[m][n][r] * pI[m][r] * qI[n]
                        - accT[m][n][r] * pT[m][r] * qT[n];
                local += wp[m][r] * wq[n] * d * d;
            }
    local *= factor;
    red[tid] = local; __syncthreads();
    for (int s = 128; s; s >>= 1) { if (tid < s) red[tid] += red[tid + s]; __syncthreads(); }
    if (tid == 0) grampart[wg] = red[0];
}

// ---------------------------------------------------------------- kernel 5
__global__ __launch_bounds__(256) void k_final(const float* __restrict__ simpart,
                                               const float* __restrict__ grampart,
                                               int ngram,
                                               float* __restrict__ out) {
    __shared__ float red[256];
    int t = threadIdx.x;
    float v = (t < BT) ? simpart[t] : 0.f;
    float g = 0.f;
    for (int i = t; i < ngram; i += 256) g += grampart[i];
    v += 10.f * g;
    red[t] = v; __syncthreads();
    for (int s = 128; s; s >>= 1) { if (t < s) red[t] += red[t + s]; __syncthreads(); }
    if (t == 0) out[0] = red[0] * (1.f / BT);
}

// ---------------------------------------------------------------- launch
extern "C" void kernel_launch(void* const* d_in, const int* in_sizes, int n_in,
                              void* d_out, int out_size, void* d_ws, size_t ws_size,
                              hipStream_t stream) {
    (void)in_sizes; (void)n_in; (void)out_size;
    const float* in = (const float*)d_in[0];
    const float* tg = (const float*)d_in[1];

    const size_t f8Bytes   = (size_t)NROWS * DIM;          // one fp8 matrix (12.6 MB)
    const size_t floatsOff = 2 * f8Bytes;
    const size_t fCount    = 5 * (size_t)NROWS + (size_t)NWG_N * DIM
                           + (size_t)BT * DIM + DIM + BT + NGRAM;
    const size_t needed    = floatsOff + fCount * 4;
    const bool   pre       = ws_size >= needed;

    char* wsb = (char*)d_ws;
    unsigned char* in8 = nullptr;
    unsigned char* tg8 = nullptr;
    float* fbase;
    if (pre) {
        in8   = (unsigned char*)wsb;
        tg8   = (unsigned char*)(wsb + f8Bytes);
        fbase = (float*)(wsb + floatsOff);
    } else {
        fbase = (float*)wsb;
    }
    float* inv_in  = fbase;
    float* inv_tg  = fbase + NROWS;
    float* ploss   = fbase + 2 * (size_t)NROWS;
    float* wraw    = fbase + 3 * (size_t)NROWS;
    float* weights = fbase + 4 * (size_t)NROWS;
    float* psum    = fbase + 5 * (size_t)NROWS;            // NWG_N*DIM (6.3 MB)
    float* bsum    = psum + (size_t)NWG_N * DIM;           // BT*DIM
    float* va      = bsum + (size_t)BT * DIM;              // DIM
    float* simpart = va + DIM;                             // BT
    float* grampart= simpart + BT;                         // NGRAM

    if (pre) {
        k_norms<1><<<NWG_N, 512, 0, stream>>>(in, tg, inv_in, inv_tg, ploss, in8, tg8, psum);
    } else {
        k_norms<0><<<NWG_N, 512, 0, stream>>>(in, tg, inv_in, inv_tg, ploss, nullptr, nullptr, psum);
    }
    k_bsum2<<<dim3(BT, 3), 256, 0, stream>>>(psum, bsum);
    k_gmean<<<3, 256, 0, stream>>>(bsum, va);
    k_wdots<<<NROWS / 16, 256, 0, stream>>>(tg, inv_tg, bsum, va, wraw);
    k_wfinal<<<BT, 256, 0, stream>>>(wraw, ploss, weights, simpart);
    if (pre) {
        k_gram<<<NGRAM, 256, 0, stream>>>(in8, tg8, weights, grampart);
    } else {
        k_gram_f32<<<NGRAM, 256, 0, stream>>>(in, tg, inv_in, inv_tg, weights, grampart);
    }
    k_final<<<1, 256, 0, stream>>>(simpart, grampart, NGRAM, (float*)d_out);
}

// Round 14
// 66.775 us; speedup vs baseline: 1.1032x; 1.0230x over previous
//
#include <hip/hip_runtime.h>
#include <hip/hip_bf16.h>

#define NROWS 16384
#define DIM   768
#define PP    256
#define BT    64
#define EPSF  1e-6f
#define GKC   32     // k_gram K-chunk (elements; = bytes in fp8)
#define NTILE 10     // symmetric 64x64 tile pairs per block
#define NGRAM (BT * NTILE)   // 640 WGs
#define SPITCH 776   // LDS f32 pitch for psum staging
#define RPW    16    // rows per norm WG (1024 threads, wave per row)
#define NWG_N  (NROWS / RPW)   // 1024 WGs
#define F8SCALE 32.0f          // pre-scale before fp8 cast (exact pow2)
#define F8INV   (1.0f / 1024.0f) // undo SCALE^2 on raw gram entries

typedef short          bf16x8 __attribute__((ext_vector_type(8)));
typedef float          f32x4  __attribute__((ext_vector_type(4)));
typedef unsigned short us8    __attribute__((ext_vector_type(8)));

__device__ __forceinline__ unsigned short f2bf(float x) {
    __hip_bfloat16 h = __float2bfloat16(x);
    return *reinterpret_cast<unsigned short*>(&h);
}

// pack 4 f32 -> 4 fp8 e4m3 bytes (OCP on gfx950)
__device__ __forceinline__ unsigned int pk_fp8x4(float a, float b, float c, float d) {
    int w = __builtin_amdgcn_cvt_pk_fp8_f32(a, b, 0, false);
    w = __builtin_amdgcn_cvt_pk_fp8_f32(c, d, w, true);
    return (unsigned int)w;
}

// ---------------------------------------------------------------- kernel 1
// Per-row inv-norms + patch_loss + fused partial block-sum of normalized
// target rows + fp8(e4m3, x32) premat. 1024 threads = 16 waves, wave/row.
// `in` is loaded nontemporal (single-use stream; clang ext_vector type —
// HIP float4 is rejected by the builtin); `tg` stays cached for k_wdots.
template<int PRE>
__global__ __launch_bounds__(1024, 4) void k_norms(const float* __restrict__ in,
                                                   const float* __restrict__ tg,
                                                   float* __restrict__ inv_in,
                                                   float* __restrict__ inv_tg,
                                                   float* __restrict__ ploss,
                                                   unsigned char* __restrict__ in8,
                                                   unsigned char* __restrict__ tg8,
                                                   float* __restrict__ psum) {
    __shared__ __align__(16) float S[RPW][SPITCH];   // 49.7 KB
    const int r   = threadIdx.x >> 6;          // row within WG (0..15)
    const int c   = threadIdx.x & 63;          // lane
    const int row = blockIdx.x * RPW + r;
    const f32x4* ip = (const f32x4*)(in + (size_t)row * DIM);
    const f32x4* tp = (const f32x4*)(tg + (size_t)row * DIM);
    f32x4 a[3], t[3];
#pragma unroll
    for (int k = 0; k < 3; ++k) {
        a[k] = __builtin_nontemporal_load(&ip[c + 64 * k]);
        t[k] = tp[c + 64 * k];
    }
    float si = 0.f, st = 0.f, sd = 0.f;
#pragma unroll
    for (int k = 0; k < 3; ++k) {
        si += a[k].x*a[k].x + a[k].y*a[k].y + a[k].z*a[k].z + a[k].w*a[k].w;
        st += t[k].x*t[k].x + t[k].y*t[k].y + t[k].z*t[k].z + t[k].w*t[k].w;
        float dx = a[k].x-t[k].x, dy = a[k].y-t[k].y, dz = a[k].z-t[k].z, dw = a[k].w-t[k].w;
        sd += dx*dx + dy*dy + dz*dz + dw*dw;
    }
#pragma unroll
    for (int o = 32; o; o >>= 1) {
        si += __shfl_xor(si, o); st += __shfl_xor(st, o); sd += __shfl_xor(sd, o);
    }
    float ii = 1.f / fmaxf(sqrtf(si), 1e-12f);
    float it = 1.f / fmaxf(sqrtf(st), 1e-12f);
    if (c == 0) { inv_in[row] = ii; inv_tg[row] = it; ploss[row] = sd * (1.f / DIM); }

    // stage normalized tg (f32) for the fused block-sum
#pragma unroll
    for (int k = 0; k < 3; ++k) {
        f32x4 u = t[k] * it;
        *(f32x4*)&S[r][4 * c + 256 * k] = u;
    }

    if constexpr (PRE != 0) {
        float is = ii * F8SCALE, ts = it * F8SCALE;
#pragma unroll
        for (int k = 0; k < 3; ++k) {
            unsigned int wa = pk_fp8x4(a[k].x * is, a[k].y * is, a[k].z * is, a[k].w * is);
            unsigned int wt = pk_fp8x4(t[k].x * ts, t[k].y * ts, t[k].z * ts, t[k].w * ts);
            *(unsigned int*)(in8 + (size_t)row * DIM + 4 * c + 256 * k) = wa;
            *(unsigned int*)(tg8 + (size_t)row * DIM + 4 * c + 256 * k) = wt;
        }
    }

    __syncthreads();
    // deterministic 16-row reduce: thread d (<768) sums its column
    {
        int d = threadIdx.x;
        if (d < DIM) {
            float s = 0.f;
#pragma unroll
            for (int rr = 0; rr < RPW; ++rr) s += S[rr][d];
            psum[(size_t)blockIdx.x * DIM + d] = s;
        }
    }
}

// ------------------------------------------- weights pipeline (all f32!)
// tf/idf denominators are near-zero means with values at the eps=1e-6 pole
// scale — bf16/fp8 dot error ~1e-6 lands ON the pole (round-3 absmax 1.68).
// Everything feeding the reciprocals stays f32.

// merge 16 psum partials per block -> bsum[b][d]
__global__ __launch_bounds__(256) void k_bsum2(const float* __restrict__ psum,
                                               float* __restrict__ bsum) {
    int b = blockIdx.x, d = blockIdx.y * 256 + threadIdx.x;
    float s = 0.f;
#pragma unroll 8
    for (int i = 0; i < 16; ++i)
        s += psum[(size_t)(b * 16 + i) * DIM + d];
    bsum[b * DIM + d] = s;
}

// global mean vector
__global__ __launch_bounds__(256) void k_gmean(const float* __restrict__ bsum,
                                               float* __restrict__ va) {
    int d = blockIdx.x * 256 + threadIdx.x;
    float g = 0.f;
    for (int b = 0; b < BT; ++b) g += bsum[b * DIM + d];
    va[d] = g * (1.f / NROWS);
}

__global__ __launch_bounds__(256) void k_wdots(const float* __restrict__ tg,
                                               const float* __restrict__ inv_tg,
                                               const float* __restrict__ bsum,
                                               const float* __restrict__ va,
                                               float* __restrict__ wraw) {
    int wave = threadIdx.x >> 6, lane = threadIdx.x & 63;
    int gw = blockIdx.x * 4 + wave;
#pragma unroll
    for (int rr = 0; rr < 4; ++rr) {
        int row = gw * 4 + rr;
        int b   = row >> 8;
        const float4* t4 = (const float4*)(tg + (size_t)row * DIM);
        const float4* b4 = (const float4*)(bsum + b * DIM);
        const float4* a4 = (const float4*)va;
        float db = 0.f, da = 0.f;
#pragma unroll
        for (int v = 0; v < 3; ++v) {
            float4 t = t4[lane + 64 * v];
            float4 x = b4[lane + 64 * v];
            float4 y = a4[lane + 64 * v];
            db += t.x * x.x + t.y * x.y + t.z * x.z + t.w * x.w;
            da += t.x * y.x + t.y * y.y + t.z * y.z + t.w * y.w;
        }
#pragma unroll
        for (int o = 32; o; o >>= 1) { db += __shfl_xor(db, o); da += __shfl_xor(da, o); }
        if (lane == 0) {
            float itg = inv_tg[row];
            db *= itg; da *= itg;
            wraw[row] = (1.f / (db * (1.f / PP) + EPSF)) * (1.f / (da + EPSF));
        }
    }
}

__global__ __launch_bounds__(256) void k_wfinal(const float* __restrict__ wraw,
                                                const float* __restrict__ ploss,
                                                float* __restrict__ weights,
                                                float* __restrict__ simpart) {
    __shared__ float red[256];
    int b = blockIdx.x, p = threadIdx.x, row = b * PP + p;
    float w = wraw[row];
    red[p] = w; __syncthreads();
    for (int s = 128; s; s >>= 1) { if (p < s) red[p] += red[p + s]; __syncthreads(); }
    float wn = w / (red[0] + EPSF);
    weights[row] = wn;
    __syncthreads();
    red[p] = wn * ploss[row]; __syncthreads();
    for (int s = 128; s; s >>= 1) { if (p < s) red[p] += red[p + s]; __syncthreads(); }
    if (p == 0) simpart[b] = red[0];
}

// ---------------------------------------------------------------- kernel 4
// Dual-gram from fp8(x32) premat: 640 WGs = 64 blocks x 10 symmetric 64x64
// tile pairs; 4 waves, each a 32x32 quadrant of BOTH grams via
// mfma_f32_16x16x32_fp8_fp8. Double-buffered 16 KB LDS, one barrier/K-step.
__global__ __launch_bounds__(256, 4) void k_gram(const unsigned char* __restrict__ in8,
                                                 const unsigned char* __restrict__ tg8,
                                                 const float* __restrict__ weights,
                                                 float* __restrict__ grampart) {
    __shared__ __align__(16) unsigned char L[2][4][64 * GKC];
    __shared__ float red[256];

    const int wg  = blockIdx.x;
    const int xcd = wg & 7, j = wg >> 3;          // 640 = 8 XCD chunks x 80
    const int b   = xcd * 8 + j / NTILE;
    const int t   = j % NTILE;
    int ti, tj;
    if (t < 4)      { ti = 0; tj = t; }
    else if (t < 7) { ti = 1; tj = t - 3; }
    else if (t < 9) { ti = 2; tj = t - 5; }
    else            { ti = 3; tj = 3; }
    const int pr = ti * 64, qc = tj * 64;
    const bool diag = (ti == tj);
    const float factor = diag ? 1.f : 2.f;
    const int bP = b * PP;

    const int tid = threadIdx.x, lane = tid & 63, wave = tid >> 6;

    const unsigned char* smat = (wave & 1) ? tg8 : in8;
    const int  srow0   = bP + ((wave < 2) ? pr : qc);
    const bool doStage = !(diag && wave >= 2);
    const int  srl = lane >> 2;
    const int  scc = lane & 3;
    const int  wcc = scc ^ (srl & 3);

    unsigned long long sreg[4];
    auto LD = [&](int k0) {
        if (!doStage) return;
#pragma unroll
        for (int i = 0; i < 4; ++i)
            sreg[i] = *(const unsigned long long*)(smat + (size_t)(srow0 + 16 * i + srl) * DIM + k0 + scc * 8);
    };
    auto WR = [&](int cur) {
        if (!doStage) return;
#pragma unroll
        for (int i = 0; i < 4; ++i)
            *(unsigned long long*)&L[cur][wave][(16 * i + srl) * GKC + wcc * 8] = sreg[i];
    };

    const int ar0 = (wave >> 1) * 32, bc0 = (wave & 1) * 32;
    const int rl = lane & 15, kc = lane >> 4;
    const int bi_ = diag ? 0 : 2, bt_ = diag ? 1 : 3;

    f32x4 accI[2][2], accT[2][2];
#pragma unroll
    for (int m = 0; m < 2; ++m)
#pragma unroll
        for (int n = 0; n < 2; ++n) {
            f32x4 z = { 0.f, 0.f, 0.f, 0.f };
            accI[m][n] = z; accT[m][n] = z;
        }

    LD(0); WR(0);
    int cur = 0;
    const int NS = DIM / GKC;   // 24
    for (int ks = 0; ks < NS; ++ks) {
        if (ks + 1 < NS) LD((ks + 1) * GKC);
        __syncthreads();
        long long aI[2], aT[2], bI[2], bT[2];
#pragma unroll
        for (int m = 0; m < 2; ++m) {
            int row = ar0 + m * 16 + rl;
            int off = row * GKC + ((kc ^ (row & 3)) << 3);
            aI[m] = *(const long long*)&L[cur][0][off];
            aT[m] = *(const long long*)&L[cur][1][off];
        }
#pragma unroll
        for (int n = 0; n < 2; ++n) {
            int row = bc0 + n * 16 + rl;
            int off = row * GKC + ((kc ^ (row & 3)) << 3);
            bI[n] = *(const long long*)&L[cur][bi_][off];
            bT[n] = *(const long long*)&L[cur][bt_][off];
        }
#pragma unroll
        for (int m = 0; m < 2; ++m)
#pragma unroll
            for (int n = 0; n < 2; ++n) {
                accI[m][n] = __builtin_amdgcn_mfma_f32_16x16x32_fp8_fp8(aI[m], bI[n], accI[m][n], 0, 0, 0);
                accT[m][n] = __builtin_amdgcn_mfma_f32_16x16x32_fp8_fp8(aT[m], bT[n], accT[m][n], 0, 0, 0);
            }
        if (ks + 1 < NS) WR(cur ^ 1);
        cur ^= 1;
    }

    const int r4 = lane >> 4, cl = lane & 15;
    float wq[2], wp[2][4];
#pragma unroll
    for (int n = 0; n < 2; ++n) wq[n] = weights[bP + qc + bc0 + n * 16 + cl];
#pragma unroll
    for (int m = 0; m < 2; ++m)
#pragma unroll
        for (int r = 0; r < 4; ++r) wp[m][r] = weights[bP + pr + ar0 + m * 16 + r4 * 4 + r];
    float local = 0.f;
#pragma unroll
    for (int m = 0; m < 2; ++m)
#pragma unroll
        for (int n = 0; n < 2; ++n)
#pragma unroll
            for (int r = 0; r < 4; ++r) {
                float d = (accI[m][n][r] - accT[m][n][r]) * F8INV;
                local += wp[m][r] * wq[n] * d * d;
            }
    local *= factor;
    red[tid] = local; __syncthreads();
    for (int s = 128; s; s >>= 1) { if (tid < s) red[tid] += red[tid + s]; __syncthreads(); }
    if (tid == 0) grampart[wg] = red[0];
}

// ------------------------------------------- fallback gram (f32 staging,
// bf16 MFMA, inv-norm in epilogue) — used only if workspace too small.
__global__ __launch_bounds__(256, 3) void k_gram_f32(const float* __restrict__ in,
                                                     const float* __restrict__ tg,
                                                     const float* __restrict__ inv_in,
                                                     const float* __restrict__ inv_tg,
                                                     const float* __restrict__ weights,
                                                     float* __restrict__ grampart) {
    __shared__ __align__(16) unsigned short L[2][4][64 * GKC];
    __shared__ float red[256];

    const int wg  = blockIdx.x;
    const int xcd = wg & 7, j = wg >> 3;
    const int b   = xcd * 8 + j / NTILE;
    const int t   = j % NTILE;
    int ti, tj;
    if (t < 4)      { ti = 0; tj = t; }
    else if (t < 7) { ti = 1; tj = t - 3; }
    else if (t < 9) { ti = 2; tj = t - 5; }
    else            { ti = 3; tj = 3; }
    const int pr = ti * 64, qc = tj * 64;
    const bool diag = (ti == tj);
    const float factor = diag ? 1.f : 2.f;
    const int bP = b * PP;

    const int tid = threadIdx.x, lane = tid & 63, wave = tid >> 6;

    const float* smat = (wave & 1) ? tg : in;
    const int  srow0   = bP + ((wave < 2) ? pr : qc);
    const bool doStage = !(diag && wave >= 2);
    const int  srl = lane >> 2;
    const int  scc = lane & 3;
    const int  wcc = scc ^ (srl & 3);

    float4 p0[4], p1[4];
    auto LD = [&](int k0) {
        if (!doStage) return;
#pragma unroll
        for (int i = 0; i < 4; ++i) {
            const float* base = smat + (size_t)(srow0 + 16 * i + srl) * DIM + k0 + scc * 8;
            p0[i] = *(const float4*)base;
            p1[i] = *(const float4*)(base + 4);
        }
    };
    auto WR = [&](int cur) {
        if (!doStage) return;
#pragma unroll
        for (int i = 0; i < 4; ++i) {
            us8 v;
            v[0] = f2bf(p0[i].x); v[1] = f2bf(p0[i].y);
            v[2] = f2bf(p0[i].z); v[3] = f2bf(p0[i].w);
            v[4] = f2bf(p1[i].x); v[5] = f2bf(p1[i].y);
            v[6] = f2bf(p1[i].z); v[7] = f2bf(p1[i].w);
            *(us8*)&L[cur][wave][(16 * i + srl) * GKC + wcc * 8] = v;
        }
    };

    const int ar0 = (wave >> 1) * 32, bc0 = (wave & 1) * 32;
    const int rl = lane & 15, kc = lane >> 4;
    const int bi_ = diag ? 0 : 2, bt_ = diag ? 1 : 3;

    f32x4 accI[2][2], accT[2][2];
#pragma unroll
    for (int m = 0; m < 2; ++m)
#pragma unroll
        for (int n = 0; n < 2; ++n) {
            f32x4 z = { 0.f, 0.f, 0.f, 0.f };
            accI[m][n] = z; accT[m][n] = z;
        }

    LD(0); WR(0);
    int cur = 0;
    const int NS = DIM / GKC;
    for (int ks = 0; ks < NS; ++ks) {
        if (ks + 1 < NS) LD((ks + 1) * GKC);
        __syncthreads();
        bf16x8 aI[2], aT[2], bI[2], bT[2];
#pragma unroll
        for (int m = 0; m < 2; ++m) {
            int row = ar0 + m * 16 + rl;
            int off = row * GKC + ((kc ^ (row & 3)) << 3);
            aI[m] = *(const bf16x8*)&L[cur][0][off];
            aT[m] = *(const bf16x8*)&L[cur][1][off];
        }
#pragma unroll
        for (int n = 0; n < 2; ++n) {
            int row = bc0 + n * 16 + rl;
            int off = row * GKC + ((kc ^ (row & 3)) << 3);
            bI[n] = *(const bf16x8*)&L[cur][bi_][off];
            bT[n] = *(const bf16x8*)&L[cur][bt_][off];
        }
#pragma unroll
        for (int m = 0; m < 2; ++m)
#pragma unroll
            for (int n = 0; n < 2; ++n) {
                accI[m][n] = __builtin_amdgcn_mfma_f32_16x16x32_bf16(aI[m], bI[n], accI[m][n], 0, 0, 0);
                accT[m][n] = __builtin_amdgcn_mfma_f32_16x16x32_bf16(aT[m], bT[n], accT[m][n], 0, 0, 0);
            }
        if (ks + 1 < NS) WR(cur ^ 1);
        cur ^= 1;
    }

    const int r4 = lane >> 4, cl = lane & 15;
    float wq[2], qI[2], qT[2];
#pragma unroll
    for (int n = 0; n < 2; ++n) {
        int q = bP + qc + bc0 + n * 16 + cl;
        wq[n] = weights[q]; qI[n] = inv_in[q]; qT[n] = inv_tg[q];
    }
    float wp[2][4], pI[2][4], pT[2][4];
#pragma unroll
    for (int m = 0; m < 2; ++m)
#pragma unroll
        for (int r = 0; r < 4; ++r) {
            int p = bP + pr + ar0 + m * 16 + r4 * 4 + r;
            wp[m][r] = weights[p]; pI[m][r] = inv_in[p]; pT[m][r] = inv_tg[p];
        }
    float local = 0.f;
#pragma unroll
    for (int m = 0; m < 2; ++m)
#pragma unroll
        for (int n = 0; n < 2; ++n)
#pragma unroll
            for (int r = 0; r < 4; ++r) {
                float d = accI[m][n][r] * pI[m][r] * qI[n]
                        - accT[m][n][r] * pT[m][r] * qT[n];
                local += wp[m][r] * wq[n] * d * d;
            }
    local *= factor;
    red[tid] = local; __syncthreads();
    for (int s = 128; s; s >>= 1) { if (tid < s) red[tid] += red[tid + s]; __syncthreads(); }
    if (tid == 0) grampart[wg] = red[0];
}

// ---------------------------------------------------------------- kernel 5
__global__ __launch_bounds__(256) void k_final(const float* __restrict__ simpart,
                                               const float* __restrict__ grampart,
                                               int ngram,
                                               float* __restrict__ out) {
    __shared__ float red[256];
    int t = threadIdx.x;
    float v = (t < BT) ? simpart[t] : 0.f;
    float g = 0.f;
    for (int i = t; i < ngram; i += 256) g += grampart[i];
    v += 10.f * g;
    red[t] = v; __syncthreads();
    for (int s = 128; s; s >>= 1) { if (t < s) red[t] += red[t + s]; __syncthreads(); }
    if (t == 0) out[0] = red[0] * (1.f / BT);
}

// ---------------------------------------------------------------- launch
extern "C" void kernel_launch(void* const* d_in, const int* in_sizes, int n_in,
                              void* d_out, int out_size, void* d_ws, size_t ws_size,
                              hipStream_t stream) {
    (void)in_sizes; (void)n_in; (void)out_size;
    const float* in = (const float*)d_in[0];
    const float* tg = (const float*)d_in[1];

    const size_t f8Bytes   = (size_t)NROWS * DIM;          // one fp8 matrix (12.6 MB)
    const size_t floatsOff = 2 * f8Bytes;
    const size_t fCount    = 5 * (size_t)NROWS + (size_t)NWG_N * DIM
                           + (size_t)BT * DIM + DIM + BT + NGRAM;
    const size_t needed    = floatsOff + fCount * 4;
    const bool   pre       = ws_size >= needed;

    char* wsb = (char*)d_ws;
    unsigned char* in8 = nullptr;
    unsigned char* tg8 = nullptr;
    float* fbase;
    if (pre) {
        in8   = (unsigned char*)wsb;
        tg8   = (unsigned char*)(wsb + f8Bytes);
        fbase = (float*)(wsb + floatsOff);
    } else {
        fbase = (float*)wsb;
    }
    float* inv_in  = fbase;
    float* inv_tg  = fbase + NROWS;
    float* ploss   = fbase + 2 * (size_t)NROWS;
    float* wraw    = fbase + 3 * (size_t)NROWS;
    float* weights = fbase + 4 * (size_t)NROWS;
    float* psum    = fbase + 5 * (size_t)NROWS;            // NWG_N*DIM (3.1 MB)
    float* bsum    = psum + (size_t)NWG_N * DIM;           // BT*DIM
    float* va      = bsum + (size_t)BT * DIM;              // DIM
    float* simpart = va + DIM;                             // BT
    float* grampart= simpart + BT;                         // NGRAM

    if (pre) {
        k_norms<1><<<NWG_N, 1024, 0, stream>>>(in, tg, inv_in, inv_tg, ploss, in8, tg8, psum);
    } else {
        k_norms<0><<<NWG_N, 1024, 0, stream>>>(in, tg, inv_in, inv_tg, ploss, nullptr, nullptr, psum);
    }
    k_bsum2<<<dim3(BT, 3), 256, 0, stream>>>(psum, bsum);
    k_gmean<<<3, 256, 0, stream>>>(bsum, va);
    k_wdots<<<NROWS / 16, 256, 0, stream>>>(tg, inv_tg, bsum, va, wraw);
    k_wfinal<<<BT, 256, 0, stream>>>(wraw, ploss, weights, simpart);
    if (pre) {
        k_gram<<<NGRAM, 256, 0, stream>>>(in8, tg8, weights, grampart);
    } else {
        k_gram_f32<<<NGRAM, 256, 0, stream>>>(in, tg, inv_in, inv_tg, weights, grampart);
    }
    k_final<<<1, 256, 0, stream>>>(simpart, grampart, NGRAM, (float*)d_out);
}